// Round 1
// baseline (643.951 us; speedup 1.0000x reference)
//
#include <hip/hip_runtime.h>

typedef __attribute__((ext_vector_type(8))) __bf16 bf16x8;
typedef __attribute__((ext_vector_type(4))) __bf16 bf16x4;
typedef __attribute__((ext_vector_type(4))) float f32x4;

#define SEQ 1024
#define NH 32
#define PD 64
#define ND 128
#define CLEN 64
#define NCHUNK 16

// LDS row strides (elements); all row strides keep 16B row alignment for b128 reads
#define CS_LD 136   // C staged row-major [64][136] bf16
#define BT_LD 72    // B staged transposed (n-major) [128][72] bf16
#define XT_LD 72    // X transposed (p-major) [64][72] bf16
#define SS_LD 72    // S (masked/decayed) row-major [64][72] bf16
#define SR_LD 136   // running-state bf16 mirror [64][136]

// XOR swizzle key for BsT/XsT in-row element index. Key on (row>>2)&7 so the
// 4-element staging scatter (n = 4k+j, j fixed) sees 8 distinct keys across k
// -> staging writes drop from ~16-way to ~4-way conflicts, and phase (a)'s
// column gather drops from ~8-way to ~2-way. Key is 8-element aligned so
// b128 reads stay legal (XOR of an 8-aligned offset with bits 3..5 maps an
// aligned 8-elem group to an aligned 8-elem group, element order preserved).
__device__ __forceinline__ int swz(int r) { return ((r >> 2) & 7) << 3; }

// Raw barrier: LDS-only visibility (lgkmcnt), NO vmcnt drain -> register
// prefetch of the next chunk's globals survives across all 4 barriers/chunk.
// No global-memory communication crosses these barriers (Y is write-only,
// state hand-off is via LDS), so dropping the vmcnt(0) drain is safe.
__device__ __forceinline__ void barrier_lds() {
    asm volatile("s_waitcnt lgkmcnt(0)" ::: "memory");
    __builtin_amdgcn_s_barrier();
    asm volatile("" ::: "memory");
}

__global__ __launch_bounds__(512, 2)
void ssd_fused(const float* __restrict__ Xg, const float* __restrict__ Ag,
               const float* __restrict__ Bg, const float* __restrict__ Cg,
               float* __restrict__ Yg)
{
    __shared__ __align__(16) float cumA[64];
    __shared__ __align__(16) float eA[64];
    __shared__ __align__(16) float dxA[64];
    __shared__ __align__(16) float scal[4];
    __shared__ __align__(16) __bf16 Cs[64 * CS_LD];
    __shared__ __align__(16) __bf16 BsT[128 * BT_LD];
    __shared__ __align__(16) __bf16 XsT[64 * XT_LD];
    __shared__ __align__(16) __bf16 Ss[64 * SS_LD];
    __shared__ __align__(16) __bf16 SrB[64 * SR_LD];

    const int tid  = threadIdx.x;
    const int w    = tid >> 6;
    const int lane = tid & 63;
    const int q    = lane >> 4;   // quad within wave
    const int ln   = lane & 15;
    const int m4   = w & 3;       // M-strip (rows 16*m4..+15)
    const int h2   = w >> 2;      // half split for N tiles

    const int bh = blockIdx.x;
    const int b  = bh >> 5;
    const int h  = bh & 31;

    const float* Xb = Xg + (size_t)b * SEQ * NH * PD + (size_t)h * PD;
    const float* Ab = Ag + (size_t)b * SEQ * NH + h;
    const float* Bb = Bg + (size_t)b * SEQ * NH * ND + (size_t)h * ND;
    const float* Cb = Cg + (size_t)b * SEQ * NH * ND + (size_t)h * ND;
    float*       Yb = Yg + (size_t)b * SEQ * NH * PD + (size_t)h * PD;

    // zero the bf16 state mirror (read by phase (d) in chunk 0)
    {
        unsigned int* p0 = (unsigned int*)SrB;
        for (int i = tid; i < 64 * SR_LD / 2; i += 512) p0[i] = 0u;
    }
    f32x4 srun[4];
    #pragma unroll
    for (int t = 0; t < 4; ++t) srun[t] = (f32x4){0.f, 0.f, 0.f, 0.f};
    __syncthreads();

    // ---------------- prologue: load chunk 0 into registers ----------------
    f32x4 creg[4], breg[4], xreg[2];
    float areg = 0.f;
    #define LOAD_CHUNK(S0) do {                                                   \
        _Pragma("unroll")                                                         \
        for (int i = 0; i < 4; ++i) {                                             \
            int v   = tid + 512 * i;                                              \
            int row = v >> 5;                                                     \
            int c4  = (v & 31) << 2;                                              \
            creg[i] = *(const f32x4*)(Cb + (size_t)((S0) + row) * (NH * ND) + c4);\
            breg[i] = *(const f32x4*)(Bb + (size_t)((S0) + row) * (NH * ND) + c4);\
        }                                                                         \
        _Pragma("unroll")                                                         \
        for (int i = 0; i < 2; ++i) {                                             \
            int v   = tid + 512 * i;                                              \
            int row = v >> 4;                                                     \
            int c4  = (v & 15) << 2;                                              \
            xreg[i] = *(const f32x4*)(Xb + (size_t)((S0) + row) * (NH * PD) + c4);\
        }                                                                         \
        if (w == 0) areg = Ab[(size_t)((S0) + lane) * NH];                        \
    } while (0)

    LOAD_CHUNK(0);

    for (int c = 0; c < NCHUNK; ++c) {
        const int s0 = c * CLEN;

        // ---------------- stage current regs -> LDS (bf16, swizzled) --------
        #pragma unroll
        for (int i = 0; i < 4; ++i) {
            int v   = tid + 512 * i;
            int row = v >> 5;
            int c4  = (v & 31) << 2;
            bf16x4 cv;
            cv[0] = (__bf16)creg[i][0]; cv[1] = (__bf16)creg[i][1];
            cv[2] = (__bf16)creg[i][2]; cv[3] = (__bf16)creg[i][3];
            *(bf16x4*)&Cs[row * CS_LD + c4] = cv;
            #pragma unroll
            for (int j = 0; j < 4; ++j) {
                int n = c4 + j;
                BsT[n * BT_LD + (row ^ swz(n))] = (__bf16)breg[i][j];
            }
        }
        #pragma unroll
        for (int i = 0; i < 2; ++i) {
            int v   = tid + 512 * i;
            int row = v >> 4;
            int c4  = (v & 15) << 2;
            #pragma unroll
            for (int j = 0; j < 4; ++j) {
                int p = c4 + j;
                XsT[p * XT_LD + (row ^ swz(p))] = (__bf16)xreg[i][j];
            }
        }

        // ---------------- wave 0: inclusive scan of A (64) -------------------
        if (w == 0) {
            float v = areg;
            #pragma unroll
            for (int off = 1; off < 64; off <<= 1) {
                float u = __shfl_up(v, off, 64);
                if (lane >= off) v += u;
            }
            float alast = __shfl(v, 63, 64);
            cumA[lane] = v;
            eA[lane]   = __expf(v);            // state_decay_out
            dxA[lane]  = __expf(alast - v);    // decay_states
            if (lane == 0) scal[0] = __expf(alast);
        }

        // ---------------- prefetch chunk c+1 into registers ------------------
        // Issued before S1; consumed at next iteration's staging (after S4).
        // barrier_lds() never drains vmcnt, so these stay in flight across the
        // entire compute of chunk c.
        if (c + 1 < NCHUNK) LOAD_CHUNK((c + 1) * CLEN);

        barrier_lds();  // S1: staged tiles + scan results visible

        // ---------------- (a): S = tril-decay(C @ B^T) -> Ss -----------------
        {
            const int arow = 16 * m4 + ln;
            f32x4 ca = *(const f32x4*)&cumA[16 * m4 + 4 * q];  // cumA[lrow] per r
            #pragma unroll
            for (int t = 0; t < 2; ++t) {
                const int sn   = 2 * h2 + t;
                const int scol = 16 * sn + ln;
                if (sn <= m4) {
                    f32x4 acc = (f32x4){0.f, 0.f, 0.f, 0.f};
                    #pragma unroll
                    for (int kt = 0; kt < 4; ++kt) {
                        bf16x8 af = *(const bf16x8*)&Cs[arow * CS_LD + kt * 32 + q * 8];
                        bf16x8 bq;
                        #pragma unroll
                        for (int j = 0; j < 8; ++j) {
                            int n = kt * 32 + q * 8 + j;
                            bq[j] = BsT[n * BT_LD + (scol ^ swz(n))];
                        }
                        acc = __builtin_amdgcn_mfma_f32_16x16x32_bf16(af, bq, acc, 0, 0, 0);
                    }
                    float csc = cumA[scol];
                    #pragma unroll
                    for (int r = 0; r < 4; ++r) {
                        int lrow  = 16 * m4 + 4 * q + r;
                        float val = (lrow >= scol) ? acc[r] * __expf(ca[r] - csc) : 0.f;
                        Ss[lrow * SS_LD + scol] = (__bf16)val;
                    }
                } else {
                    #pragma unroll
                    for (int r = 0; r < 4; ++r)
                        Ss[(16 * m4 + 4 * q + r) * SS_LD + scol] = (__bf16)0.f;
                }
            }
        }

        barrier_lds();  // S2: Ss ready

        // ---------------- (b)+(d): Y = S'@X + diag(eA)*(C @ S_run^T) ---------
        f32x4 yacc[2], yoff[2];
        yacc[0] = (f32x4){0.f, 0.f, 0.f, 0.f};
        yacc[1] = (f32x4){0.f, 0.f, 0.f, 0.f};
        yoff[0] = (f32x4){0.f, 0.f, 0.f, 0.f};
        yoff[1] = (f32x4){0.f, 0.f, 0.f, 0.f};
        {
            const int arow = 16 * m4 + ln;
            // (b): K-steps above the diagonal strip are entirely zero -> skip
            for (int kt = 0; kt <= (m4 >> 1); ++kt) {
                bf16x8 af = *(const bf16x8*)&Ss[arow * SS_LD + kt * 32 + q * 8];
                #pragma unroll
                for (int t = 0; t < 2; ++t) {
                    int prow = 16 * (2 * h2 + t) + ln;
                    bf16x8 bq = *(const bf16x8*)&XsT[prow * XT_LD + ((kt * 32 + q * 8) ^ swz(prow))];
                    yacc[t] = __builtin_amdgcn_mfma_f32_16x16x32_bf16(af, bq, yacc[t], 0, 0, 0);
                }
            }
            // (d): raw C @ S_run^T; eA row-scale folded in the epilogue
            #pragma unroll
            for (int kt = 0; kt < 4; ++kt) {
                bf16x8 craw = *(const bf16x8*)&Cs[arow * CS_LD + kt * 32 + q * 8];
                #pragma unroll
                for (int t = 0; t < 2; ++t) {
                    int pt = 2 * h2 + t;
                    bf16x8 bq = *(const bf16x8*)&SrB[(16 * pt + ln) * SR_LD + kt * 32 + q * 8];
                    yoff[t] = __builtin_amdgcn_mfma_f32_16x16x32_bf16(craw, bq, yoff[t], 0, 0, 0);
                }
            }
            // epilogue fold: yacc[t][r] += eA[lrow(r)] * yoff[t][r]
            f32x4 ev = *(const f32x4*)&eA[16 * m4 + 4 * q];
            #pragma unroll
            for (int t = 0; t < 2; ++t)
                #pragma unroll
                for (int r = 0; r < 4; ++r)
                    yacc[t][r] += ev[r] * yoff[t][r];
        }

        // ---------------- (c): states = (X^T * dexp) @ B ---------------------
        f32x4 sacc[4];
        #pragma unroll
        for (int t = 0; t < 4; ++t) sacc[t] = (f32x4){0.f, 0.f, 0.f, 0.f};
        {
            const int prow = 16 * m4 + ln;
            #pragma unroll
            for (int kt = 0; kt < 2; ++kt) {
                bf16x8 xv = *(const bf16x8*)&XsT[prow * XT_LD + ((kt * 32 + q * 8) ^ swz(prow))];
                f32x4 d0 = *(const f32x4*)&dxA[kt * 32 + q * 8];
                f32x4 d1 = *(const f32x4*)&dxA[kt * 32 + q * 8 + 4];
                bf16x8 af;
                #pragma unroll
                for (int j = 0; j < 4; ++j) {
                    af[j]     = (__bf16)((float)xv[j] * d0[j]);
                    af[4 + j] = (__bf16)((float)xv[4 + j] * d1[j]);
                }
                #pragma unroll
                for (int t = 0; t < 4; ++t) {
                    int nrow = 16 * (4 * h2 + t) + ln;
                    bf16x8 bq = *(const bf16x8*)&BsT[nrow * BT_LD + ((kt * 32 + q * 8) ^ swz(nrow))];
                    sacc[t] = __builtin_amdgcn_mfma_f32_16x16x32_bf16(af, bq, sacc[t], 0, 0, 0);
                }
            }
        }

        barrier_lds();  // S3: all LDS readers (SrB, Cs, BsT, XsT, Ss) done

        // ---------------- state update + SrB refresh + Y store ---------------
        {
            float elast = scal[0];
            #pragma unroll
            for (int t = 0; t < 4; ++t) {
                int ncol = 16 * (4 * h2 + t) + ln;
                #pragma unroll
                for (int r = 0; r < 4; ++r) {
                    float s = elast * srun[t][r] + sacc[t][r];
                    srun[t][r] = s;
                    SrB[(16 * m4 + 4 * q + r) * SR_LD + ncol] = (__bf16)s;
                }
            }
            #pragma unroll
            for (int t = 0; t < 2; ++t) {
                int pcol = 16 * (2 * h2 + t) + ln;
                #pragma unroll
                for (int r = 0; r < 4; ++r) {
                    int lrow = 16 * m4 + 4 * q + r;
                    Yb[(size_t)(s0 + lrow) * (NH * PD) + pcol] = yacc[t][r];
                }
            }
        }

        barrier_lds();  // S4: SrB refresh visible; staged buffers free for c+1
    }
    #undef LOAD_CHUNK
}

extern "C" void kernel_launch(void* const* d_in, const int* in_sizes, int n_in,
                              void* d_out, int out_size, void* d_ws, size_t ws_size,
                              hipStream_t stream) {
    const float* X = (const float*)d_in[0];
    const float* A = (const float*)d_in[1];
    const float* B = (const float*)d_in[2];
    const float* C = (const float*)d_in[3];
    float* Y = (float*)d_out;
    dim3 grid(512, 1, 1), block(512, 1, 1);
    hipLaunchKernelGGL(ssd_fused, grid, block, 0, stream, X, A, B, C, Y);
}